// Round 16
// baseline (114.076 us; speedup 1.0000x reference)
//
#include <hip/hip_runtime.h>

#define DI __device__ __forceinline__

typedef unsigned short u16;
typedef short short8 __attribute__((ext_vector_type(8)));
typedef float f32x2 __attribute__((ext_vector_type(2)));
typedef float f32x4 __attribute__((ext_vector_type(4)));
typedef float f32x16 __attribute__((ext_vector_type(16)));
typedef u16 u16x4 __attribute__((ext_vector_type(4)));
typedef unsigned u32x4 __attribute__((ext_vector_type(4)));
typedef int i32x2 __attribute__((ext_vector_type(2)));

// round-to-nearest-even f32 -> bf16
DI u16 f2bf(float f){
    unsigned u = __builtin_bit_cast(unsigned, f);
    u += 0x7FFFu + ((u >> 16) & 1u);
    return (u16)(u >> 16);
}
DI float bf2f(u16 b){
    unsigned u = ((unsigned)b) << 16;
    return __builtin_bit_cast(float, u);
}

#if defined(__has_builtin)
#if __has_builtin(__builtin_amdgcn_global_load_lds)
#define HAS_GLL 1
#endif
#if __has_builtin(__builtin_amdgcn_exp2f)
#define HAS_EXP2 1
#endif
#if __has_builtin(__builtin_amdgcn_permlane32_swap)
#define HAS_PL32 1
#endif
#endif

DI void async16(u16* lds, const u16* g){
#ifdef HAS_GLL
    __builtin_amdgcn_global_load_lds(
        (const __attribute__((address_space(1))) unsigned int*)g,
        (__attribute__((address_space(3))) unsigned int*)lds, 16, 0, 0);
#else
    *(short8*)lds = *(const short8*)g;
#endif
}

DI float ex2(float x){
#ifdef HAS_EXP2
    return __builtin_amdgcn_exp2f(x);
#else
    return exp2f(x);
#endif
}

// v_cvt_pk_bf16_f32: word = (bf16(lo) | bf16(hi)<<16)
DI unsigned cvtpk(float lo, float hi){
    unsigned r;
    asm("v_cvt_pk_bf16_f32 %0, %1, %2" : "=v"(r) : "v"(lo), "v"(hi));
    return r;
}

// permlane32_swap: ret[0] = {a[0:31], b[0:31]}, ret[1] = {a[32:63], b[32:63]}
DI i32x2 plswap(int a, int b){
#ifdef HAS_PL32
    return __builtin_amdgcn_permlane32_swap(a, b, false, false);
#else
    i32x2 r;
    int ax = __shfl_xor(a, 32), bx = __shfl_xor(b, 32);
    int hi = (threadIdx.x & 63) >> 5;
    r[0] = hi ? bx : a;
    r[1] = hi ? b : ax;
    return r;
#endif
}

// ---------------- constants ----------------
// B=2, N=2048, DIM_IN=DIM_K=DIM_V=1024, NH=16, hd=64
#define SEQ   2048
#define DIN   1024
#define MTOT  4096   // B*N
// Q prescale: (1/sqrt(64)) * log2(e) so softmax runs in exp2 domain
#define QSCALE 0.18033688011112042f

// ---------------- fused prep: x->bf16 + W transposes (one launch) ----------------
__global__ void k_prep(const float* __restrict__ x,
                       const float* __restrict__ Wq, const float* __restrict__ Wk,
                       const float* __restrict__ Wv,
                       u16* __restrict__ xb, u16* __restrict__ Wt3){
    __shared__ float t[32][33];
    int bid = blockIdx.x, tid = threadIdx.x;
    if (bid < 4096){
        int i = (bid * 256 + tid) * 4;
        f32x4 v = *(const f32x4*)(x + i);
        u16x4 o;
        #pragma unroll
        for (int j = 0; j < 4; j++) o[j] = f2bf(v[j]);
        *(u16x4*)(xb + i) = o;
    } else {
        int tb = bid - 4096;                      // 0..3071
        int z  = tb >> 10;                        // 0..2
        int t2 = tb & 1023;
        const float* W = (z == 0) ? Wq : (z == 1) ? Wk : Wv;
        u16* Wt = Wt3 + (size_t)z * DIN * DIN;
        int tx = tid & 31, ty = tid >> 5;         // 32 x 8
        int n0 = (t2 & 31) * 32, k0 = (t2 >> 5) * 32;
        #pragma unroll
        for (int i = 0; i < 4; i++)
            t[ty + i*8][tx] = W[(size_t)(k0 + ty + i*8) * DIN + n0 + tx];
        __syncthreads();
        #pragma unroll
        for (int i = 0; i < 4; i++)
            Wt[(size_t)(n0 + ty + i*8) * DIN + k0 + tx] = f2bf(t[tx][ty + i*8]);
    }
}

// ---------------- fused QKV projection GEMM (R13-proven) ----------------
// 128x128 tile, BK=32, 2-buffer LDS, 1-barrier/iter counted-vmcnt schedule.
// Q/K epilogue: LDS-transposed, coalesced 16B stores. V: direct u16x4.
__global__ __launch_bounds__(256, 3) void k_projf(const u16* __restrict__ A,
                                                  const u16* __restrict__ Wt3,
                                                  const float* __restrict__ bq,
                                                  const float* __restrict__ bk,
                                                  const float* __restrict__ bv,
                                                  u16* __restrict__ qb,
                                                  u16* __restrict__ kb,
                                                  u16* __restrict__ vtb){
    __shared__ __align__(16) u16 As[2][4096];
    __shared__ __align__(16) u16 Bs[2][4096];
    int tid = threadIdx.x;
    int l = tid & 63, w = tid >> 6;
    int lq = l & 15, lg = l >> 4;
    int wm = w >> 1, wn = w & 1;
    int by  = blockIdx.y;                 // 0..23
    int mat = by >> 3;                    // 0=Q 1=K 2=V
    int m0 = blockIdx.x * 128, n0 = (by & 7) * 128;
    const u16* Bt = Wt3 + (size_t)mat * DIN * DIN;
    const float* bias = (mat == 0) ? bq : (mat == 1) ? bk : bv;

    int r0 = tid >> 2, c0 = (tid & 3) * 8;
    const u16* ap0 = A  + (size_t)(m0 + r0)      * DIN + c0;
    const u16* ap1 = A  + (size_t)(m0 + 64 + r0) * DIN + c0;
    const u16* bp0 = Bt + (size_t)(n0 + r0)      * DIN + c0;
    const u16* bp1 = Bt + (size_t)(n0 + 64 + r0) * DIN + c0;
    int d0 = tid * 8, d1 = 2048 + tid * 8;

#define PSTAGE(bi) {                                              \
    async16(&As[bi][d0], ap0); async16(&As[bi][d1], ap1);         \
    async16(&Bs[bi][d0], bp0); async16(&Bs[bi][d1], bp1);         \
    ap0 += 32; ap1 += 32; bp0 += 32; bp1 += 32; }

    f32x4 acc[4][4] = {};
    PSTAGE(0)                                  // prologue: tile 0

    for (int t = 0; t < 32; t++){
        int cur = t & 1;
        if (t + 1 < 32) PSTAGE(cur ^ 1)        // issued post prior barrier -> race-free
        if (t == 0){
            asm volatile("s_waitcnt vmcnt(4)" ::: "memory");
            __builtin_amdgcn_s_barrier();
        }

        short8 af[4], bf[4];
        #pragma unroll
        for (int f = 0; f < 4; f++){
            af[f] = *(const short8*)&As[cur][(wm*64 + f*16 + lq) * 32 + lg * 8];
            bf[f] = *(const short8*)&Bs[cur][(wn*64 + f*16 + lq) * 32 + lg * 8];
        }
        __builtin_amdgcn_s_setprio(1);
        #pragma unroll
        for (int fm = 0; fm < 4; fm++)
            #pragma unroll
            for (int fn = 0; fn < 4; fn++)
                acc[fm][fn] = __builtin_amdgcn_mfma_f32_16x16x32_bf16(af[fm], bf[fn], acc[fm][fn], 0, 0, 0);
        __builtin_amdgcn_s_setprio(0);

        asm volatile("s_waitcnt vmcnt(0)" ::: "memory");
        __builtin_amdgcn_s_barrier();          // one barrier/iter
    }
#undef PSTAGE

    if (mat == 2){
        // V -> [bh][dv][n] transposed; direct u16x4 (8B/lane) stores
        for (int fn = 0; fn < 4; fn++){
            int cc = n0 + wn*64 + fn*16 + lq;
            float bvv = bias[cc];
            int hh = cc >> 6, d = cc & 63;
            for (int fm = 0; fm < 4; fm++){
                int mbase = m0 + wm*64 + fm*16 + lg*4;
                int b = mbase >> 11, n = mbase & 2047;
                u16x4 pv;
                for (int r = 0; r < 4; r++) pv[r] = f2bf(acc[fm][fn][r] + bvv);
                *(u16x4*)&vtb[((size_t)(b*16 + hh) * 64 + d) * SEQ + n] = pv;
            }
        }
    } else {
        // Q/K -> [bh][n][64]: LDS transpose then coalesced 16B stores.
        u16* dst = (mat == 0) ? qb : kb;
        float sc = (mat == 0) ? QSCALE : 1.0f;
        u16* Cs = &As[0][0];                   // 32*136*2B = 8.5 KB
        float bvv[4];
        #pragma unroll
        for (int fn = 0; fn < 4; fn++) bvv[fn] = bias[n0 + wn*64 + fn*16 + lq];

        for (int fm = 0; fm < 4; fm++){
            __syncthreads();
            #pragma unroll
            for (int fn = 0; fn < 4; fn++){
                int c = wn*64 + fn*16 + lq;
                #pragma unroll
                for (int r = 0; r < 4; r++)
                    Cs[(wm*16 + lg*4 + r)*136 + c] = f2bf((acc[fm][fn][r] + bvv[fn]) * sc);
            }
            __syncthreads();
            #pragma unroll
            for (int j = 0; j < 2; j++){
                int wr = (tid >> 4) + j*16;            // 0..31
                int coloff = (tid & 15) * 8;           // 0..120
                int ng = m0 + (wr >> 4)*64 + fm*16 + (wr & 15);
                int b = ng >> 11, n = ng & 2047;
                int cg = n0 + coloff;
                int hh = cg >> 6, d = cg & 63;
                *(short8*)&dst[((size_t)(b*16 + hh) * SEQ + n) * 64 + d] =
                    *(const short8*)&Cs[wr*136 + coloff];
            }
        }
    }
}

// ---------------- flash attention ----------------
// R12-proven inner loop (32q/wave, 2-buf K+V, exp2-direct softmax) +
// (a) XCD-aware bijective block swizzle: each XCD serves 4 contiguous heads
//     -> K/V footprint ~2.5 MB fits the per-XCD 4 MB L2 (T1).
// (b) 32 KB LDS + launch_bounds(256,5) -> 5 resident blocks/CU; S=4 grid
//     (2048 blocks) staggers block starts, breaking the phase-locked convoy.
#define MFMA32(a, b, c) __builtin_amdgcn_mfma_f32_32x32x16_bf16(a, b, c, 0, 0, 0)

#define MAKE_PA(dst, S, base) {                                   \
    unsigned a0 = cvtpk(S[base+0], S[base+1]);                    \
    unsigned a1 = cvtpk(S[base+2], S[base+3]);                    \
    unsigned b0 = cvtpk(S[base+4], S[base+5]);                    \
    unsigned b1 = cvtpk(S[base+6], S[base+7]);                    \
    i32x2 r0 = plswap((int)a0, (int)b0);                          \
    i32x2 r1 = plswap((int)a1, (int)b1);                          \
    u32x4 wv = {(unsigned)r0[0], (unsigned)r1[0],                 \
                (unsigned)r0[1], (unsigned)r1[1]};                \
    dst = __builtin_bit_cast(short8, wv); }

template<int SPLIT>
__global__ __launch_bounds__(256, 5) void k_attn(const u16* __restrict__ Q,
                                                 const u16* __restrict__ K,
                                                 const u16* __restrict__ Vt,
                                                 float* __restrict__ out,
                                                 u16* __restrict__ po,
                                                 float* __restrict__ mls){
    __shared__ __align__(16) u16 Ks[2][4096];
    __shared__ __align__(16) u16 Vs[2][4096];

    int tid = threadIdx.x, l = tid & 63, w = tid >> 6;
    int lq = l & 31, hi = l >> 5;

    // XCD-aware bijective swizzle: dispatch id -> work id d, bh-major within XCD
    int bid = (blockIdx.z * 32 + blockIdx.y) * 16 + blockIdx.x;
    const int nwg = 512 * SPLIT;
    int d = (bid & 7) * (nwg >> 3) + (bid >> 3);
    const int perbh = 16 * SPLIT;
    int bh = d / perbh;
    int rem = d - bh * perbh;
    int sp = rem >> 4;
    int qx = rem & 15;

    int b = bh >> 4, h = bh & 15;
    int q0 = qx * 128 + w * 32;
    int kvb = sp * (SEQ / SPLIT);
    const int NT = (SEQ / SPLIT) / 64;

    const u16* Qb = Q  + (size_t)bh * SEQ * 64;
    const u16* Kb = K  + (size_t)bh * SEQ * 64;
    const u16* Vb = Vt + (size_t)bh * 64 * SEQ;

    // staging source pointers (source-side swizzle: chunk c -> c ^ (row&7))
    int row0 = tid >> 3;                          // 0..31 (j=0); j=1 adds 32
    int c0   = (tid & 7) ^ (row0 & 7);
    const u16* kp0 = Kb + (size_t)(kvb + row0)      * 64 + c0 * 8;
    const u16* kp1 = Kb + (size_t)(kvb + row0 + 32) * 64 + c0 * 8;
    const u16* vp0 = Vb + (size_t)row0        * SEQ + kvb + c0 * 8;
    const u16* vp1 = Vb + (size_t)(row0 + 32) * SEQ + kvb + c0 * 8;
    int d0 = tid * 8, d1 = 2048 + tid * 8;

#define STAGE(bi) {                                               \
    async16(&Ks[bi][d0], kp0); async16(&Ks[bi][d1], kp1);         \
    async16(&Vs[bi][d0], vp0); async16(&Vs[bi][d1], vp1);         \
    kp0 += 64*64; kp1 += 64*64; vp0 += 64; vp1 += 64; }

    short8 qf[4];
    #pragma unroll
    for (int ks = 0; ks < 4; ks++)
        qf[ks] = *(const short8*)(Qb + (size_t)(q0 + lq) * 64 + ks*16 + hi*8);

    STAGE(0)

    float m = 0.f;                                 // exp2-domain shift (0 unless guard fires)
    float ls = 0.f;
    f32x16 o0 = {}, o1 = {};
    int rx = (lq & 7) << 4;                        // read-side XOR (byte units)

    for (int t = 0; t < NT; t++){
        int cur = t & 1;
        if (t + 1 < NT) STAGE(cur ^ 1)             // issued post prior barrier -> race-free
        if (t == 0){
            if (NT > 1) asm volatile("s_waitcnt vmcnt(4)" ::: "memory");
            else        asm volatile("s_waitcnt vmcnt(0)" ::: "memory");
            __builtin_amdgcn_s_barrier();
        }

        const char* kB = (const char*)&Ks[cur][0];
        const char* vB = (const char*)&Vs[cur][0];

        // ---- QK^T: St[kc][q] ----
        f32x16 st0 = {}, st1 = {};
        __builtin_amdgcn_s_setprio(1);
        #pragma unroll
        for (int ks = 0; ks < 4; ks++){
            int cb = ((ks*2 + hi) << 4) ^ rx;
            short8 ka = *(const short8*)(kB + lq*128        + cb);
            short8 kb = *(const short8*)(kB + (32+lq)*128   + cb);
            st0 = MFMA32(ka, qf[ks], st0);
            st1 = MFMA32(kb, qf[ks], st1);
        }
        __builtin_amdgcn_s_setprio(0);

        // ---- rare shift fixup (m != 0 only after an overflow-guard fire) ----
        if (m != 0.f){
            #pragma unroll
            for (int r = 0; r < 16; r++){ st0[r] -= m; st1[r] -= m; }
        }

        // ---- P = exp2(S) directly (no max reduction), packed-pair sum ----
        f32x2 ps = {0.f, 0.f};
        #pragma unroll
        for (int r = 0; r < 16; r += 2){
            st0[r]   = ex2(st0[r]);
            st0[r+1] = ex2(st0[r+1]);
            st1[r]   = ex2(st1[r]);
            st1[r+1] = ex2(st1[r+1]);
            f32x2 a = {st0[r], st0[r+1]};
            f32x2 c = {st1[r], st1[r+1]};
            ps += a + c;
        }
        float psum = ps[0] + ps[1];
        psum += __shfl_xor(psum, 32);

        // ---- P -> bf16 A-fragments ----
        short8 pa0, pa1, pa2, pa3;
        MAKE_PA(pa0, st0, 0)
        MAKE_PA(pa1, st0, 8)
        MAKE_PA(pa2, st1, 0)
        MAKE_PA(pa3, st1, 8)

        // ---- PV ----
        __builtin_amdgcn_s_setprio(1);
        #pragma unroll
        for (int kct = 0; kct < 4; kct++){
            short8 pf = (kct == 0) ? pa0 : (kct == 1) ? pa1 : (kct == 2) ? pa2 : pa3;
            int cb = ((kct*2 + hi) << 4) ^ rx;
            short8 v0 = *(const short8*)(vB + lq*128      + cb);
            short8 v1 = *(const short8*)(vB + (32+lq)*128 + cb);
            o0 = MFMA32(pf, v0, o0);
            o1 = MFMA32(pf, v1, o1);
        }
        __builtin_amdgcn_s_setprio(0);

        ls += psum;
        // ---- overflow guard (practically never fires) ----
        if (__any(ls > 1.0e30f)){
            const float dn = 5.421010862427522e-20f;   // 2^-64
            ls *= dn;
            #pragma unroll
            for (int r = 0; r < 16; r++){ o0[r] *= dn; o1[r] *= dn; }
            m += 64.f;
        }

        asm volatile("s_waitcnt vmcnt(0)" ::: "memory");   // next tile landed (covered by compute)
        __builtin_amdgcn_s_barrier();
    }

    if (SPLIT == 1){
        #pragma unroll
        for (int r = 0; r < 16; r++){
            int row = (r & 3) + 8*(r >> 2) + 4*hi;
            float inv = 1.0f / __shfl(ls, row);
            float* op = out + ((size_t)b * SEQ + (q0 + row)) * 1024 + h*64 + lq;
            op[0]  = o0[r] * inv;
            op[32] = o1[r] * inv;
        }
    } else {
        u16* pb = po + (size_t)sp * MTOT * 1024;
        #pragma unroll
        for (int r = 0; r < 16; r++){
            int row = (r & 3) + 8*(r >> 2) + 4*hi;
            u16* op = pb + ((size_t)b * SEQ + (q0 + row)) * 1024 + h*64 + lq;
            op[0]  = f2bf(o0[r]);
            op[32] = f2bf(o1[r]);
        }
        if (hi == 0){
            float* mp = mls + (((size_t)sp*32 + bh) * SEQ + (q0 + lq)) * 2;
            mp[0] = m; mp[1] = ls;
        }
    }
#undef STAGE
}

// ---------------- split combine (po is bf16) ----------------
template<int S>
__global__ __launch_bounds__(256) void k_comb(const u16* __restrict__ po,
                                              const float* __restrict__ mls,
                                              float* __restrict__ out){
    size_t i = ((size_t)blockIdx.x * 256 + threadIdx.x) * 4;
    size_t row = i >> 10;
    int col = (int)(i & 1023);
    int b = (int)(row >> 11), n = (int)(row & 2047);
    int bh = b*16 + (col >> 6);

    float mv[S], lv[S], wv[S];
    float M = -INFINITY;
    #pragma unroll
    for (int s = 0; s < S; s++){
        const float* p = mls + (((size_t)s*32 + bh) * SEQ + n) * 2;
        mv[s] = p[0]; lv[s] = p[1];
        M = fmaxf(M, mv[s]);
    }
    float L = 0.f;
    #pragma unroll
    for (int s = 0; s < S; s++){ wv[s] = ex2(mv[s] - M); L += wv[s] * lv[s]; }
    float inv = 1.0f / L;
    f32x4 acc = {};
    #pragma unroll
    for (int s = 0; s < S; s++){
        u16x4 v = *(const u16x4*)(po + (size_t)s * MTOT * 1024 + i);
        #pragma unroll
        for (int j = 0; j < 4; j++) acc[j] += wv[s] * bf2f(v[j]);
    }
    acc *= inv;
    *(f32x4*)(out + i) = acc;
}

// ---------------- launcher ----------------
extern "C" void kernel_launch(void* const* d_in, const int* in_sizes, int n_in,
                              void* d_out, int out_size, void* d_ws, size_t ws_size,
                              hipStream_t stream){
    const float* x  = (const float*)d_in[0];
    const float* Wq = (const float*)d_in[1];
    const float* bq = (const float*)d_in[2];
    const float* Wk = (const float*)d_in[3];
    const float* bk = (const float*)d_in[4];
    const float* Wv = (const float*)d_in[5];
    const float* bv = (const float*)d_in[6];
    float* out = (float*)d_out;

    const size_t MB = (size_t)1 << 20;
    if (ws_size < 38 * MB) return;

    char* ws = (char*)d_ws;
    u16* xb   = (u16*)(ws);             //  8 MB: x bf16 [4096][1024]
    u16* wt3  = (u16*)(ws +  8 * MB);   //  6 MB: Wt bf16 [3][1024][1024]
    u16* qb   = (u16*)(ws + 14 * MB);   //  8 MB: Q  [32][2048][64]
    u16* kb   = (u16*)(ws + 22 * MB);   //  8 MB: K  [32][2048][64]
    u16* vtb  = (u16*)(ws + 30 * MB);   //  8 MB: Vt [32][64][2048]
    int S = 1;
    if      (ws_size >= 38 * MB + 4 * 9 * MB) S = 4;
    else if (ws_size >= 38 * MB + 2 * 9 * MB) S = 2;
    u16* po    = (u16*)(ws + 38 * MB);                        // S x 8 MB (bf16)
    float* mls = (float*)(ws + 38 * MB + (size_t)S * 8 * MB); // S x 0.5 MB

    k_prep<<<7168, 256, 0, stream>>>(x, Wq, Wk, Wv, xb, wt3);

    k_projf<<<dim3(32, 24), 256, 0, stream>>>(xb, wt3, bq, bk, bv, qb, kb, vtb);

    if (S == 4){
        k_attn<4><<<dim3(16, 32, 4), 256, 0, stream>>>(qb, kb, vtb, out, po, mls);
        k_comb<4><<<4096, 256, 0, stream>>>(po, mls, out);
    } else if (S == 2){
        k_attn<2><<<dim3(16, 32, 2), 256, 0, stream>>>(qb, kb, vtb, out, po, mls);
        k_comb<2><<<4096, 256, 0, stream>>>(po, mls, out);
    } else {
        k_attn<1><<<dim3(16, 32, 1), 256, 0, stream>>>(qb, kb, vtb, out, po, mls);
    }
}

// Round 17
// 94.485 us; speedup vs baseline: 1.2074x; 1.2074x over previous
//
#include <hip/hip_runtime.h>

#define DI __device__ __forceinline__

typedef unsigned short u16;
typedef short short8 __attribute__((ext_vector_type(8)));
typedef float f32x2 __attribute__((ext_vector_type(2)));
typedef float f32x4 __attribute__((ext_vector_type(4)));
typedef float f32x16 __attribute__((ext_vector_type(16)));
typedef u16 u16x4 __attribute__((ext_vector_type(4)));
typedef unsigned u32x4 __attribute__((ext_vector_type(4)));
typedef int i32x2 __attribute__((ext_vector_type(2)));

// round-to-nearest-even f32 -> bf16
DI u16 f2bf(float f){
    unsigned u = __builtin_bit_cast(unsigned, f);
    u += 0x7FFFu + ((u >> 16) & 1u);
    return (u16)(u >> 16);
}
DI float bf2f(u16 b){
    unsigned u = ((unsigned)b) << 16;
    return __builtin_bit_cast(float, u);
}

#if defined(__has_builtin)
#if __has_builtin(__builtin_amdgcn_global_load_lds)
#define HAS_GLL 1
#endif
#if __has_builtin(__builtin_amdgcn_exp2f)
#define HAS_EXP2 1
#endif
#if __has_builtin(__builtin_amdgcn_permlane32_swap)
#define HAS_PL32 1
#endif
#endif

DI void async16(u16* lds, const u16* g){
#ifdef HAS_GLL
    __builtin_amdgcn_global_load_lds(
        (const __attribute__((address_space(1))) unsigned int*)g,
        (__attribute__((address_space(3))) unsigned int*)lds, 16, 0, 0);
#else
    *(short8*)lds = *(const short8*)g;
#endif
}

DI float ex2(float x){
#ifdef HAS_EXP2
    return __builtin_amdgcn_exp2f(x);
#else
    return exp2f(x);
#endif
}

// v_cvt_pk_bf16_f32: word = (bf16(lo) | bf16(hi)<<16)
DI unsigned cvtpk(float lo, float hi){
    unsigned r;
    asm("v_cvt_pk_bf16_f32 %0, %1, %2" : "=v"(r) : "v"(lo), "v"(hi));
    return r;
}

// permlane32_swap: ret[0] = {a[0:31], b[0:31]}, ret[1] = {a[32:63], b[32:63]}
DI i32x2 plswap(int a, int b){
#ifdef HAS_PL32
    return __builtin_amdgcn_permlane32_swap(a, b, false, false);
#else
    i32x2 r;
    int ax = __shfl_xor(a, 32), bx = __shfl_xor(b, 32);
    int hi = (threadIdx.x & 63) >> 5;
    r[0] = hi ? bx : a;
    r[1] = hi ? b : ax;
    return r;
#endif
}

// ---------------- constants ----------------
// B=2, N=2048, DIM_IN=DIM_K=DIM_V=1024, NH=16, hd=64
#define SEQ   2048
#define DIN   1024
#define MTOT  4096   // B*N
// Q prescale: (1/sqrt(64)) * log2(e) so softmax runs in exp2 domain
#define QSCALE 0.18033688011112042f

// ---------------- fused prep: x->bf16 + W transposes (one launch) ----------------
__global__ void k_prep(const float* __restrict__ x,
                       const float* __restrict__ Wq, const float* __restrict__ Wk,
                       const float* __restrict__ Wv,
                       u16* __restrict__ xb, u16* __restrict__ Wt3){
    __shared__ float t[32][33];
    int bid = blockIdx.x, tid = threadIdx.x;
    if (bid < 4096){
        int i = (bid * 256 + tid) * 4;
        f32x4 v = *(const f32x4*)(x + i);
        u16x4 o;
        #pragma unroll
        for (int j = 0; j < 4; j++) o[j] = f2bf(v[j]);
        *(u16x4*)(xb + i) = o;
    } else {
        int tb = bid - 4096;                      // 0..3071
        int z  = tb >> 10;                        // 0..2
        int t2 = tb & 1023;
        const float* W = (z == 0) ? Wq : (z == 1) ? Wk : Wv;
        u16* Wt = Wt3 + (size_t)z * DIN * DIN;
        int tx = tid & 31, ty = tid >> 5;         // 32 x 8
        int n0 = (t2 & 31) * 32, k0 = (t2 >> 5) * 32;
        #pragma unroll
        for (int i = 0; i < 4; i++)
            t[ty + i*8][tx] = W[(size_t)(k0 + ty + i*8) * DIN + n0 + tx];
        __syncthreads();
        #pragma unroll
        for (int i = 0; i < 4; i++)
            Wt[(size_t)(n0 + ty + i*8) * DIN + k0 + tx] = f2bf(t[tx][ty + i*8]);
    }
}

// ---------------- fused QKV projection GEMM (R13-proven) ----------------
// 128x128 tile, BK=32, 2-buffer LDS, 1-barrier/iter counted-vmcnt schedule.
// Q/K epilogue: LDS-transposed, coalesced 16B stores. V: direct u16x4.
__global__ __launch_bounds__(256, 3) void k_projf(const u16* __restrict__ A,
                                                  const u16* __restrict__ Wt3,
                                                  const float* __restrict__ bq,
                                                  const float* __restrict__ bk,
                                                  const float* __restrict__ bv,
                                                  u16* __restrict__ qb,
                                                  u16* __restrict__ kb,
                                                  u16* __restrict__ vtb){
    __shared__ __align__(16) u16 As[2][4096];
    __shared__ __align__(16) u16 Bs[2][4096];
    int tid = threadIdx.x;
    int l = tid & 63, w = tid >> 6;
    int lq = l & 15, lg = l >> 4;
    int wm = w >> 1, wn = w & 1;
    int by  = blockIdx.y;                 // 0..23
    int mat = by >> 3;                    // 0=Q 1=K 2=V
    int m0 = blockIdx.x * 128, n0 = (by & 7) * 128;
    const u16* Bt = Wt3 + (size_t)mat * DIN * DIN;
    const float* bias = (mat == 0) ? bq : (mat == 1) ? bk : bv;

    int r0 = tid >> 2, c0 = (tid & 3) * 8;
    const u16* ap0 = A  + (size_t)(m0 + r0)      * DIN + c0;
    const u16* ap1 = A  + (size_t)(m0 + 64 + r0) * DIN + c0;
    const u16* bp0 = Bt + (size_t)(n0 + r0)      * DIN + c0;
    const u16* bp1 = Bt + (size_t)(n0 + 64 + r0) * DIN + c0;
    int d0 = tid * 8, d1 = 2048 + tid * 8;

#define PSTAGE(bi) {                                              \
    async16(&As[bi][d0], ap0); async16(&As[bi][d1], ap1);         \
    async16(&Bs[bi][d0], bp0); async16(&Bs[bi][d1], bp1);         \
    ap0 += 32; ap1 += 32; bp0 += 32; bp1 += 32; }

    f32x4 acc[4][4] = {};
    PSTAGE(0)                                  // prologue: tile 0

    for (int t = 0; t < 32; t++){
        int cur = t & 1;
        if (t + 1 < 32) PSTAGE(cur ^ 1)        // issued post prior barrier -> race-free
        if (t == 0){
            asm volatile("s_waitcnt vmcnt(4)" ::: "memory");
            __builtin_amdgcn_s_barrier();
        }

        short8 af[4], bf[4];
        #pragma unroll
        for (int f = 0; f < 4; f++){
            af[f] = *(const short8*)&As[cur][(wm*64 + f*16 + lq) * 32 + lg * 8];
            bf[f] = *(const short8*)&Bs[cur][(wn*64 + f*16 + lq) * 32 + lg * 8];
        }
        __builtin_amdgcn_s_setprio(1);
        #pragma unroll
        for (int fm = 0; fm < 4; fm++)
            #pragma unroll
            for (int fn = 0; fn < 4; fn++)
                acc[fm][fn] = __builtin_amdgcn_mfma_f32_16x16x32_bf16(af[fm], bf[fn], acc[fm][fn], 0, 0, 0);
        __builtin_amdgcn_s_setprio(0);

        asm volatile("s_waitcnt vmcnt(0)" ::: "memory");
        __builtin_amdgcn_s_barrier();          // one barrier/iter
    }
#undef PSTAGE

    if (mat == 2){
        // V -> [bh][dv][n] transposed; direct u16x4 (8B/lane) stores
        for (int fn = 0; fn < 4; fn++){
            int cc = n0 + wn*64 + fn*16 + lq;
            float bvv = bias[cc];
            int hh = cc >> 6, d = cc & 63;
            for (int fm = 0; fm < 4; fm++){
                int mbase = m0 + wm*64 + fm*16 + lg*4;
                int b = mbase >> 11, n = mbase & 2047;
                u16x4 pv;
                for (int r = 0; r < 4; r++) pv[r] = f2bf(acc[fm][fn][r] + bvv);
                *(u16x4*)&vtb[((size_t)(b*16 + hh) * 64 + d) * SEQ + n] = pv;
            }
        }
    } else {
        // Q/K -> [bh][n][64]: LDS transpose then coalesced 16B stores.
        u16* dst = (mat == 0) ? qb : kb;
        float sc = (mat == 0) ? QSCALE : 1.0f;
        u16* Cs = &As[0][0];                   // 32*136*2B = 8.5 KB
        float bvv[4];
        #pragma unroll
        for (int fn = 0; fn < 4; fn++) bvv[fn] = bias[n0 + wn*64 + fn*16 + lq];

        for (int fm = 0; fm < 4; fm++){
            __syncthreads();
            #pragma unroll
            for (int fn = 0; fn < 4; fn++){
                int c = wn*64 + fn*16 + lq;
                #pragma unroll
                for (int r = 0; r < 4; r++)
                    Cs[(wm*16 + lg*4 + r)*136 + c] = f2bf((acc[fm][fn][r] + bvv[fn]) * sc);
            }
            __syncthreads();
            #pragma unroll
            for (int j = 0; j < 2; j++){
                int wr = (tid >> 4) + j*16;            // 0..31
                int coloff = (tid & 15) * 8;           // 0..120
                int ng = m0 + (wr >> 4)*64 + fm*16 + (wr & 15);
                int b = ng >> 11, n = ng & 2047;
                int cg = n0 + coloff;
                int hh = cg >> 6, d = cg & 63;
                *(short8*)&dst[((size_t)(b*16 + hh) * SEQ + n) * 64 + d] =
                    *(const short8*)&Cs[wr*136 + coloff];
            }
        }
    }
}

// ---------------- flash attention ----------------
// R15-proven structure (32q/wave, exp2-direct softmax, PV-defer pipeline,
// K 2-buf + V 3-buf = 40 KB, launch_bounds(256,4)) + XCD-aware bijective
// block swizzle ONLY (isolated): each XCD serves 4 contiguous heads ->
// K+V ~2 MB fits its 4 MB L2 (R16 proved FETCH halves; now measured alone).
#define MFMA32(a, b, c) __builtin_amdgcn_mfma_f32_32x32x16_bf16(a, b, c, 0, 0, 0)

#define MAKE_PA(dst, S, base) {                                   \
    unsigned a0 = cvtpk(S[base+0], S[base+1]);                    \
    unsigned a1 = cvtpk(S[base+2], S[base+3]);                    \
    unsigned b0 = cvtpk(S[base+4], S[base+5]);                    \
    unsigned b1 = cvtpk(S[base+6], S[base+7]);                    \
    i32x2 r0 = plswap((int)a0, (int)b0);                          \
    i32x2 r1 = plswap((int)a1, (int)b1);                          \
    u32x4 wv = {(unsigned)r0[0], (unsigned)r1[0],                 \
                (unsigned)r0[1], (unsigned)r1[1]};                \
    dst = __builtin_bit_cast(short8, wv); }

template<int SPLIT>
__global__ __launch_bounds__(256, 4) void k_attn(const u16* __restrict__ Q,
                                                 const u16* __restrict__ K,
                                                 const u16* __restrict__ Vt,
                                                 float* __restrict__ out,
                                                 u16* __restrict__ po,
                                                 float* __restrict__ mls){
    __shared__ __align__(16) u16 Ks[2][4096];
    __shared__ __align__(16) u16 Vs[3][4096];

    int tid = threadIdx.x, l = tid & 63, w = tid >> 6;
    int lq = l & 31, hi = l >> 5;

    // XCD-aware bijective swizzle (isolated change): bid = 8q+r -> d = r*(nwg/8)+q
    int bid = (blockIdx.z * 32 + blockIdx.y) * 16 + blockIdx.x;
    const int nwg = 512 * SPLIT;
    int d = (bid & 7) * (nwg >> 3) + (bid >> 3);
    const int perbh = 16 * SPLIT;
    int bh = d / perbh;
    int rem = d - bh * perbh;
    int sp = rem >> 4;
    int qx = rem & 15;

    int b = bh >> 4, h = bh & 15;
    int q0 = qx * 128 + w * 32;
    int kvb = sp * (SEQ / SPLIT);
    const int NT = (SEQ / SPLIT) / 64;

    const u16* Qb = Q  + (size_t)bh * SEQ * 64;
    const u16* Kb = K  + (size_t)bh * SEQ * 64;
    const u16* Vb = Vt + (size_t)bh * 64 * SEQ;

    // staging source pointers (source-side swizzle: chunk c -> c ^ (row&7))
    int row0 = tid >> 3;                          // 0..31 (j=0); j=1 adds 32
    int c0   = (tid & 7) ^ (row0 & 7);
    const u16* kp0 = Kb + (size_t)(kvb + row0)      * 64 + c0 * 8;
    const u16* kp1 = Kb + (size_t)(kvb + row0 + 32) * 64 + c0 * 8;
    const u16* vp0 = Vb + (size_t)row0        * SEQ + kvb + c0 * 8;
    const u16* vp1 = Vb + (size_t)(row0 + 32) * SEQ + kvb + c0 * 8;
    int d0 = tid * 8, d1 = 2048 + tid * 8;

#define STAGEK(bi) {                                              \
    async16(&Ks[bi][d0], kp0); async16(&Ks[bi][d1], kp1);         \
    kp0 += 64*64; kp1 += 64*64; }
#define STAGEV(bi) {                                              \
    async16(&Vs[bi][d0], vp0); async16(&Vs[bi][d1], vp1);         \
    vp0 += 64; vp1 += 64; }

    short8 qf[4];
    #pragma unroll
    for (int ks = 0; ks < 4; ks++)
        qf[ks] = *(const short8*)(Qb + (size_t)(q0 + lq) * 64 + ks*16 + hi*8);

    STAGEK(0) STAGEV(0)

    float m = 0.f;                                 // exp2-domain shift (0 unless guard fires)
    float ls = 0.f;
    f32x16 o0 = {}, o1 = {};
    short8 pa0, pa1, pa2, pa3;                     // P fragments of tile t-1
    int rx = (lq & 7) << 4;                        // read-side XOR (byte units)

    for (int t = 0; t < NT; t++){
        int kc = t & 1;
        if (t + 1 < NT){ STAGEK(kc ^ 1) STAGEV((t + 1) % 3) }
        if (t == 0){
            if (NT > 1) asm volatile("s_waitcnt vmcnt(4)" ::: "memory");
            else        asm volatile("s_waitcnt vmcnt(0)" ::: "memory");
            __builtin_amdgcn_s_barrier();
        }

        // ---- PV(t-1): operands ready (V landed long ago, pa in regs) ----
        if (t > 0){
            const char* vB = (const char*)&Vs[(t + 2) % 3][0];   // (t-1)%3
            __builtin_amdgcn_s_setprio(1);
            #pragma unroll
            for (int kct = 0; kct < 4; kct++){
                short8 pf = (kct == 0) ? pa0 : (kct == 1) ? pa1 : (kct == 2) ? pa2 : pa3;
                int cb = ((kct*2 + hi) << 4) ^ rx;
                short8 v0 = *(const short8*)(vB + lq*128      + cb);
                short8 v1 = *(const short8*)(vB + (32+lq)*128 + cb);
                o0 = MFMA32(pf, v0, o0);
                o1 = MFMA32(pf, v1, o1);
            }
            __builtin_amdgcn_s_setprio(0);
        }

        // ---- QK^T(t): St[kc][q] ----
        const char* kB = (const char*)&Ks[kc][0];
        f32x16 st0 = {}, st1 = {};
        __builtin_amdgcn_s_setprio(1);
        #pragma unroll
        for (int ks = 0; ks < 4; ks++){
            int cb = ((ks*2 + hi) << 4) ^ rx;
            short8 ka = *(const short8*)(kB + lq*128        + cb);
            short8 kb = *(const short8*)(kB + (32+lq)*128   + cb);
            st0 = MFMA32(ka, qf[ks], st0);
            st1 = MFMA32(kb, qf[ks], st1);
        }
        __builtin_amdgcn_s_setprio(0);

        // ---- rare shift fixup (m != 0 only after an overflow-guard fire) ----
        if (m != 0.f){
            #pragma unroll
            for (int r = 0; r < 16; r++){ st0[r] -= m; st1[r] -= m; }
        }

        // ---- P = exp2(S) directly (no max reduction), packed-pair sum ----
        f32x2 ps = {0.f, 0.f};
        #pragma unroll
        for (int r = 0; r < 16; r += 2){
            st0[r]   = ex2(st0[r]);
            st0[r+1] = ex2(st0[r+1]);
            st1[r]   = ex2(st1[r]);
            st1[r+1] = ex2(st1[r+1]);
            f32x2 a = {st0[r], st0[r+1]};
            f32x2 c = {st1[r], st1[r+1]};
            ps += a + c;
        }
        float psum = ps[0] + ps[1];
        psum += __shfl_xor(psum, 32);

        // ---- overflow guard BEFORE packing (pa(t) not yet consumed) ----
        if (__any(ls + psum > 1.0e30f)){
            const float dn = 5.421010862427522e-20f;   // 2^-64
            ls *= dn; psum *= dn;
            #pragma unroll
            for (int r = 0; r < 16; r++){
                o0[r] *= dn; o1[r] *= dn;
                st0[r] *= dn; st1[r] *= dn;
            }
            m += 64.f;
        }
        ls += psum;

        // ---- P -> bf16 A-fragments (consumed by PV at iter t+1) ----
        MAKE_PA(pa0, st0, 0)
        MAKE_PA(pa1, st0, 8)
        MAKE_PA(pa2, st1, 0)
        MAKE_PA(pa3, st1, 8)

        asm volatile("s_waitcnt vmcnt(0)" ::: "memory");   // next tile landed (covered by compute)
        __builtin_amdgcn_s_barrier();
    }

    // ---- final PV(NT-1) ----
    {
        const char* vB = (const char*)&Vs[(NT + 2) % 3][0];   // (NT-1)%3
        __builtin_amdgcn_s_setprio(1);
        #pragma unroll
        for (int kct = 0; kct < 4; kct++){
            short8 pf = (kct == 0) ? pa0 : (kct == 1) ? pa1 : (kct == 2) ? pa2 : pa3;
            int cb = ((kct*2 + hi) << 4) ^ rx;
            short8 v0 = *(const short8*)(vB + lq*128      + cb);
            short8 v1 = *(const short8*)(vB + (32+lq)*128 + cb);
            o0 = MFMA32(pf, v0, o0);
            o1 = MFMA32(pf, v1, o1);
        }
        __builtin_amdgcn_s_setprio(0);
    }

    if (SPLIT == 1){
        #pragma unroll
        for (int r = 0; r < 16; r++){
            int row = (r & 3) + 8*(r >> 2) + 4*hi;
            float inv = 1.0f / __shfl(ls, row);
            float* op = out + ((size_t)b * SEQ + (q0 + row)) * 1024 + h*64 + lq;
            op[0]  = o0[r] * inv;
            op[32] = o1[r] * inv;
        }
    } else {
        u16* pb = po + (size_t)sp * MTOT * 1024;
        #pragma unroll
        for (int r = 0; r < 16; r++){
            int row = (r & 3) + 8*(r >> 2) + 4*hi;
            u16* op = pb + ((size_t)b * SEQ + (q0 + row)) * 1024 + h*64 + lq;
            op[0]  = f2bf(o0[r]);
            op[32] = f2bf(o1[r]);
        }
        if (hi == 0){
            float* mp = mls + (((size_t)sp*32 + bh) * SEQ + (q0 + lq)) * 2;
            mp[0] = m; mp[1] = ls;
        }
    }
#undef STAGEK
#undef STAGEV
}

// ---------------- split combine (po is bf16) ----------------
template<int S>
__global__ __launch_bounds__(256) void k_comb(const u16* __restrict__ po,
                                              const float* __restrict__ mls,
                                              float* __restrict__ out){
    size_t i = ((size_t)blockIdx.x * 256 + threadIdx.x) * 4;
    size_t row = i >> 10;
    int col = (int)(i & 1023);
    int b = (int)(row >> 11), n = (int)(row & 2047);
    int bh = b*16 + (col >> 6);

    float mv[S], lv[S], wv[S];
    float M = -INFINITY;
    #pragma unroll
    for (int s = 0; s < S; s++){
        const float* p = mls + (((size_t)s*32 + bh) * SEQ + n) * 2;
        mv[s] = p[0]; lv[s] = p[1];
        M = fmaxf(M, mv[s]);
    }
    float L = 0.f;
    #pragma unroll
    for (int s = 0; s < S; s++){ wv[s] = ex2(mv[s] - M); L += wv[s] * lv[s]; }
    float inv = 1.0f / L;
    f32x4 acc = {};
    #pragma unroll
    for (int s = 0; s < S; s++){
        u16x4 v = *(const u16x4*)(po + (size_t)s * MTOT * 1024 + i);
        #pragma unroll
        for (int j = 0; j < 4; j++) acc[j] += wv[s] * bf2f(v[j]);
    }
    acc *= inv;
    *(f32x4*)(out + i) = acc;
}

// ---------------- launcher ----------------
extern "C" void kernel_launch(void* const* d_in, const int* in_sizes, int n_in,
                              void* d_out, int out_size, void* d_ws, size_t ws_size,
                              hipStream_t stream){
    const float* x  = (const float*)d_in[0];
    const float* Wq = (const float*)d_in[1];
    const float* bq = (const float*)d_in[2];
    const float* Wk = (const float*)d_in[3];
    const float* bk = (const float*)d_in[4];
    const float* Wv = (const float*)d_in[5];
    const float* bv = (const float*)d_in[6];
    float* out = (float*)d_out;

    const size_t MB = (size_t)1 << 20;
    if (ws_size < 38 * MB) return;

    char* ws = (char*)d_ws;
    u16* xb   = (u16*)(ws);             //  8 MB: x bf16 [4096][1024]
    u16* wt3  = (u16*)(ws +  8 * MB);   //  6 MB: Wt bf16 [3][1024][1024]
    u16* qb   = (u16*)(ws + 14 * MB);   //  8 MB: Q  [32][2048][64]
    u16* kb   = (u16*)(ws + 22 * MB);   //  8 MB: K  [32][2048][64]
    u16* vtb  = (u16*)(ws + 30 * MB);   //  8 MB: Vt [32][64][2048]
    int S = (ws_size >= 38 * MB + 2 * 9 * MB) ? 2 : 1;
    u16* po    = (u16*)(ws + 38 * MB);                        // S x 8 MB (bf16)
    float* mls = (float*)(ws + 38 * MB + (size_t)S * 8 * MB); // S x 0.5 MB

    k_prep<<<7168, 256, 0, stream>>>(x, Wq, Wk, Wv, xb, wt3);

    k_projf<<<dim3(32, 24), 256, 0, stream>>>(xb, wt3, bq, bk, bv, qb, kb, vtb);

    if (S == 2){
        k_attn<2><<<dim3(16, 32, 2), 256, 0, stream>>>(qb, kb, vtb, out, po, mls);
        k_comb<2><<<4096, 256, 0, stream>>>(po, mls, out);
    } else {
        k_attn<1><<<dim3(16, 32, 1), 256, 0, stream>>>(qb, kb, vtb, out, po, mls);
    }
}